// Round 8
// baseline (330.516 us; speedup 1.0000x reference)
//
#include <hip/hip_runtime.h>
#include <hip/hip_bf16.h>

// LSTM_80960133529703: B=16384, T=24, F=7, H=8, L=4; dense 192->1024->2048->4.
// R7: GEMM K-loop de-LDS'd on the A side: A-fragments loaded per-lane direct
//     from global (b128, row-ptr + k-imm) -> DS traffic halves (was the
//     binding pipe: 98KB/block-iter modeled ~= measured 93us). B stays
//     LDS-staged (XOR swizzle, conflict-free). Single tile/block (R3/R6
//     showed VGPR>128 halves occupancy and costs 2x). launch_bounds(256,4)
//     pins 4 waves/EU = 4 blocks/CU.
// ws: Y @0 | H1 @6291456 | W1b @39845888 | W2b @40239104
typedef __attribute__((ext_vector_type(4))) float f32x4;
typedef __attribute__((ext_vector_type(2))) float f32x2;
typedef __attribute__((ext_vector_type(8))) short bf16x8;

__device__ __forceinline__ ushort f2bf(float f) {
    union { float f; uint u; } v; v.f = f;
    uint u = v.u;
    return (ushort)((u + 0x7fffu + ((u >> 16) & 1u)) >> 16);   // RNE
}
__device__ __forceinline__ float sigm(float x) {
    return __builtin_amdgcn_rcpf(1.0f + __builtin_amdgcn_exp2f(x * -1.442695040888963f));
}
__device__ __forceinline__ float tanh_(float x) {
    return 2.0f * __builtin_amdgcn_rcpf(1.0f + __builtin_amdgcn_exp2f(x * -2.885390081777927f)) - 1.0f;
}

typedef const __attribute__((address_space(1))) unsigned int ga_u32;
typedef __attribute__((address_space(3))) unsigned int lds_u32;
__device__ __forceinline__ void g2l16(const void* g, void* l) {
    __builtin_amdgcn_global_load_lds((ga_u32*)(unsigned long long)g,
                                     (lds_u32*)(unsigned int)(unsigned long long)l,
                                     16, 0, 0);
}

// ---------------------------------------------------------------- LSTM ----
struct LstmW {
    const float* wih[4];
    const float* whh[4];
    const float* bih[4];
    const float* bhh[4];
};

__device__ __forceinline__ void gates8p(const f32x2 w01[8], const f32x2 w23[8],
                                        const float xv8[8], f32x2& a01, f32x2& a23) {
#pragma unroll
    for (int k = 0; k < 8; ++k) {
        f32x2 xv = {xv8[k], xv8[k]};
        a01 += w01[k] * xv;
        a23 += w23[k] * xv;
    }
}
__device__ __forceinline__ void cellup(f32x2 a01, f32x2 a23, float& h, float& c) {
    c = sigm(a01.y) * c + sigm(a01.x) * tanh_(a23.x);
    h = sigm(a23.y) * tanh_(c);
}
__device__ __forceinline__ void ld8(const float* p, float v[8]) {
    float4 a = *(const float4*)p;
    float4 b = *(const float4*)(p + 4);
    v[0] = a.x; v[1] = a.y; v[2] = a.z; v[3] = a.w;
    v[4] = b.x; v[5] = b.y; v[6] = b.z; v[7] = b.w;
}

// blocks [0,512): LSTM; blocks [512, 512+560): weight cvt fp32->bf16 (+ out init)
__global__ __launch_bounds__(256) void pre_kernel(const float* __restrict__ x, LstmW p,
                                                  ushort* __restrict__ Y,
                                                  const float* __restrict__ W1,
                                                  const float* __restrict__ W2,
                                                  ushort* __restrict__ W1b,
                                                  ushort* __restrict__ W2b,
                                                  const float* __restrict__ b3,
                                                  float* __restrict__ out) {
    __shared__ float xs[32 * 168];
    __shared__ float hb[32 * 200];

    const int tid = threadIdx.x;
    if (blockIdx.x >= 512) {
        // ---- cvt path: 560 blocks x 256 threads x 4 float4 = 573440 f4 ----
        const int tg = (blockIdx.x - 512) * 256 + tid;
        if (tg < 16384) {
            float4 bv = {b3[0], b3[1], b3[2], b3[3]};
            ((float4*)out)[tg] = bv;
        }
#pragma unroll
        for (int s = 0; s < 4; ++s) {
            int i = tg + s * 143360;
            const float4* src; ushort4* dst; int off;
            if (i < 49152) { src = (const float4*)W1; dst = (ushort4*)W1b; off = i; }
            else { src = (const float4*)W2; dst = (ushort4*)W2b; off = i - 49152; }
            float4 v = src[off];
            ushort4 r; r.x = f2bf(v.x); r.y = f2bf(v.y); r.z = f2bf(v.z); r.w = f2bf(v.w);
            dst[off] = r;
        }
        return;
    }

    const int e0 = blockIdx.x * 32;
    {
        const float4* s = (const float4*)(x + (size_t)e0 * 168);
        float4* d = (float4*)xs;
        for (int i = tid; i < 1344; i += 256) d[i] = s[i];
    }
    __syncthreads();

    const int el = tid >> 3, j = tid & 7;
    float* hr = hb + el * 200;
    const float* xr = xs + el * 168;

    f32x2 wx01[8], wx23[8], wh01[8], wh23[8], b01, b23;

    // ---- layer 0 (in = 7) ----
    {
        const float* Wih = p.wih[0];
        const float* Whh = p.whh[0];
#pragma unroll
        for (int k = 0; k < 7; ++k) {
            wx01[k] = {Wih[(0 + j) * 7 + k], Wih[(8 + j) * 7 + k]};
            wx23[k] = {Wih[(16 + j) * 7 + k], Wih[(24 + j) * 7 + k]};
        }
#pragma unroll
        for (int k = 0; k < 8; ++k) {
            wh01[k] = {Whh[(0 + j) * 8 + k], Whh[(8 + j) * 8 + k]};
            wh23[k] = {Whh[(16 + j) * 8 + k], Whh[(24 + j) * 8 + k]};
        }
        b01 = {p.bih[0][j] + p.bhh[0][j], p.bih[0][8 + j] + p.bhh[0][8 + j]};
        b23 = {p.bih[0][16 + j] + p.bhh[0][16 + j], p.bih[0][24 + j] + p.bhh[0][24 + j]};

        float h = 0.f, c = 0.f;
        {
            f32x2 a01 = b01, a23 = b23;
#pragma unroll
            for (int k = 0; k < 7; ++k) {
                f32x2 xv = {xr[k], xr[k]};
                a01 += wx01[k] * xv; a23 += wx23[k] * xv;
            }
            cellup(a01, a23, h, c);
            hr[j] = h;
        }
        for (int t = 1; t < 24; ++t) {
            f32x2 a01 = b01, a23 = b23;
#pragma unroll
            for (int k = 0; k < 7; ++k) {
                f32x2 xv = {xr[t * 7 + k], xr[t * 7 + k]};
                a01 += wx01[k] * xv; a23 += wx23[k] * xv;
            }
            float hp[8]; ld8(&hr[(t - 1) * 8], hp);
            gates8p(wh01, wh23, hp, a01, a23);
            cellup(a01, a23, h, c);
            hr[t * 8 + j] = h;
        }
    }

    // ---- layers 1..3 ----
#pragma unroll
    for (int l = 1; l < 4; ++l) {
        const float* Wih = p.wih[l];
        const float* Whh = p.whh[l];
#pragma unroll
        for (int k = 0; k < 8; ++k) {
            wx01[k] = {Wih[(0 + j) * 8 + k], Wih[(8 + j) * 8 + k]};
            wx23[k] = {Wih[(16 + j) * 8 + k], Wih[(24 + j) * 8 + k]};
            wh01[k] = {Whh[(0 + j) * 8 + k], Whh[(8 + j) * 8 + k]};
            wh23[k] = {Whh[(16 + j) * 8 + k], Whh[(24 + j) * 8 + k]};
        }
        b01 = {p.bih[l][j] + p.bhh[l][j], p.bih[l][8 + j] + p.bhh[l][8 + j]};
        b23 = {p.bih[l][16 + j] + p.bhh[l][16 + j], p.bih[l][24 + j] + p.bhh[l][24 + j]};

        float h = 0.f, c = 0.f;
        {
            float xin[8]; ld8(&hr[0], xin);
            f32x2 a01 = b01, a23 = b23;
            gates8p(wx01, wx23, xin, a01, a23);
            cellup(a01, a23, h, c);
            hr[j] = h;
            if (l == 3) Y[((size_t)(e0 + el) * 24) * 8 + j] = f2bf(h);
        }
        for (int t = 1; t < 24; ++t) {
            float xin[8]; ld8(&hr[t * 8], xin);
            float hp[8];  ld8(&hr[(t - 1) * 8], hp);
            f32x2 a01 = b01, a23 = b23;
            gates8p(wx01, wx23, xin, a01, a23);
            gates8p(wh01, wh23, hp, a01, a23);
            cellup(a01, a23, h, c);
            hr[t * 8 + j] = h;
            if (l == 3) Y[((size_t)(e0 + el) * 24 + t) * 8 + j] = f2bf(h);
        }
    }
}

// ---------------------------------------------------------------- GEMM ----
// Tile 128x128, BK=64, 4 waves (wave tile 64x64, 4x4 MFMA 16x16x32).
// A-side: per-lane direct global b128 frag loads (no LDS) -- lane (m16,quad)
// owns row m0+wm+mi*16+m16, k = k0 + kk*32 + quad*8 (quad folded into ptr).
// B-side: LDS [128][64] bf16 XOR-chunk-swizzled via global_load_lds (R4).
// Grid: blockIdx.x = m (fastest), blockIdx.y = n.
// FUSE3: two-pass f32 Cs[64][132] + w3s[4][132], b128 dots, atomics into out.
template <int KDIM, bool FUSE3>
__global__ __launch_bounds__(256, 4) void gemm_kernel(const ushort* __restrict__ A,
                                                      const ushort* __restrict__ W,
                                                      const float* __restrict__ bias,
                                                      ushort* __restrict__ Hout,
                                                      const float* __restrict__ W3,
                                                      float* __restrict__ outf, int N) {
    constexpr int SMEMN = FUSE3 ? 16896 : 8192;   // ushorts; FUSE3: Cs 64x132 f32
    __shared__ alignas(16) ushort smem[SMEMN];
    __shared__ alignas(16) float w3s[FUSE3 ? 528 : 1];
    ushort* Ws = smem;            // [128][64] swizzled

    const int tid = threadIdx.x;
    const int m0 = blockIdx.x * 128;
    const int n0 = blockIdx.y * 128;
    const int lane = tid & 63;
    const int wv = tid >> 6;
    const int wm = (wv & 1) * 64;
    const int wn = (wv >> 1) * 64;
    const int m16 = lane & 15;
    const int quad = lane >> 4;

    if (FUSE3) {
        for (int i = tid; i < 512; i += 256)
            w3s[(i >> 7) * 132 + (i & 127)] = W3[(size_t)(i >> 7) * 2048 + n0 + (i & 127)];
    }

    // B staging: per wave, 4 calls; call c: rows wv*32 + c*8 + lrow
    const int lrow = lane >> 3;
    const int lchunk = (lane & 7) ^ lrow;          // XOR swizzle at source
    const ushort* Wg = W + (size_t)(n0 + wv * 32 + lrow) * KDIM + lchunk * 8;
    ushort* Wld = Ws + wv * 2048;

    // A row pointers (quad folded in): frag = *(bf16x8*)(Ar[mi] + k0 + kk*32)
    const ushort* Ar[4];
#pragma unroll
    for (int mi = 0; mi < 4; ++mi)
        Ar[mi] = A + (size_t)(m0 + wm + mi * 16 + m16) * KDIM + quad * 8;

    // B frag-read swizzled chunk offsets (row&7 == m16&7)
    const int r7 = m16 & 7;
    const int ck0 = (quad ^ r7) * 8;          // kk = 0
    const int ck1 = ((quad + 4) ^ r7) * 8;    // kk = 1

    f32x4 acc[4][4];
    const f32x4 zero = {0.f, 0.f, 0.f, 0.f};
#pragma unroll
    for (int mi = 0; mi < 4; ++mi)
#pragma unroll
        for (int ni = 0; ni < 4; ++ni) acc[mi][ni] = zero;

    for (int k0 = 0; k0 < KDIM; k0 += 64) {
#pragma unroll
        for (int c = 0; c < 4; ++c)
            g2l16(Wg + (size_t)c * 8 * KDIM + k0, Wld + c * 512);

        bf16x8 afr0[4], afr1[4];
#pragma unroll
        for (int mi = 0; mi < 4; ++mi) {
            afr0[mi] = *(const bf16x8*)(Ar[mi] + k0);
            afr1[mi] = *(const bf16x8*)(Ar[mi] + k0 + 32);
        }
        __syncthreads();   // drains B stage + A frag loads (vmcnt(0))

        bf16x8 bfr[4];
#pragma unroll
        for (int ni = 0; ni < 4; ++ni)
            bfr[ni] = *(const bf16x8*)&Ws[(wn + ni * 16 + m16) * 64 + ck0];
#pragma unroll
        for (int mi = 0; mi < 4; ++mi)
#pragma unroll
            for (int ni = 0; ni < 4; ++ni)
                acc[mi][ni] = __builtin_amdgcn_mfma_f32_16x16x32_bf16(afr0[mi], bfr[ni],
                                                                     acc[mi][ni], 0, 0, 0);
#pragma unroll
        for (int ni = 0; ni < 4; ++ni)
            bfr[ni] = *(const bf16x8*)&Ws[(wn + ni * 16 + m16) * 64 + ck1];
#pragma unroll
        for (int mi = 0; mi < 4; ++mi)
#pragma unroll
            for (int ni = 0; ni < 4; ++ni)
                acc[mi][ni] = __builtin_amdgcn_mfma_f32_16x16x32_bf16(afr1[mi], bfr[ni],
                                                                     acc[mi][ni], 0, 0, 0);
        __syncthreads();
    }

    if (!FUSE3) {
#pragma unroll
        for (int ni = 0; ni < 4; ++ni) {
            const int col = n0 + wn + ni * 16 + m16;
            const float b = bias[col];
#pragma unroll
            for (int mi = 0; mi < 4; ++mi)
#pragma unroll
                for (int r = 0; r < 4; ++r) {
                    const int row = m0 + wm + mi * 16 + quad * 4 + r;
                    Hout[(size_t)row * N + col] = f2bf(fmaxf(acc[mi][ni][r] + b, 0.f));
                }
        }
    } else {
        // Two passes over 64-row halves; Cs [64][132] f32 overlays smem.
        float* Cs = (float*)smem;
        const int drow = tid >> 2;
        const int dn = tid & 3;
#pragma unroll
        for (int pass = 0; pass < 2; ++pass) {
            if ((wv & 1) == pass) {
#pragma unroll
                for (int ni = 0; ni < 4; ++ni) {
                    const int cl = wn + ni * 16 + m16;
                    const float b = bias[n0 + cl];
#pragma unroll
                    for (int mi = 0; mi < 4; ++mi)
#pragma unroll
                        for (int r = 0; r < 4; ++r) {
                            const int rl = mi * 16 + quad * 4 + r;   // 0..63
                            Cs[rl * 132 + cl] = fmaxf(acc[mi][ni][r] + b, 0.f);
                        }
                }
            }
            __syncthreads();
            const float* crow = &Cs[drow * 132];
            const float* wrow = &w3s[dn * 132];
            float p = 0.f;
#pragma unroll
            for (int ch = 0; ch < 32; ++ch) {
                f32x4 cv = *(const f32x4*)(crow + ch * 4);
                f32x4 wv4 = *(const f32x4*)(wrow + ch * 4);
                p += cv[0] * wv4[0] + cv[1] * wv4[1] + cv[2] * wv4[2] + cv[3] * wv4[3];
            }
            atomicAdd(&outf[(size_t)(m0 + pass * 64 + drow) * 4 + dn], p);
            __syncthreads();
        }
    }
}

// -------------------------------------------------------------- launch ----
extern "C" void kernel_launch(void* const* d_in, const int* in_sizes, int n_in,
                              void* d_out, int out_size, void* d_ws, size_t ws_size,
                              hipStream_t stream) {
    const float* x = (const float*)d_in[0];
    LstmW w;
    for (int l = 0; l < 4; ++l) {
        w.wih[l] = (const float*)d_in[1 + 4 * l];
        w.whh[l] = (const float*)d_in[2 + 4 * l];
        w.bih[l] = (const float*)d_in[3 + 4 * l];
        w.bhh[l] = (const float*)d_in[4 + 4 * l];
    }
    const float* Wd1 = (const float*)d_in[17];
    const float* bd1 = (const float*)d_in[18];
    const float* Wd2 = (const float*)d_in[19];
    const float* bd2 = (const float*)d_in[20];
    const float* Wd3 = (const float*)d_in[21];
    const float* bd3 = (const float*)d_in[22];
    float* out = (float*)d_out;

    ushort* Y   = (ushort*)d_ws;
    ushort* H1  = (ushort*)((char*)d_ws + 6291456);
    ushort* W1b = (ushort*)((char*)d_ws + 39845888);
    ushort* W2b = (ushort*)((char*)d_ws + 40239104);

    pre_kernel<<<1072, 256, 0, stream>>>(x, w, Y, Wd1, Wd2, W1b, W2b, bd3, out);
    gemm_kernel<192, false><<<dim3(128, 8), 256, 0, stream>>>(Y, W1b, bd1, H1, nullptr, nullptr, 1024);
    gemm_kernel<1024, true><<<dim3(128, 16), 256, 0, stream>>>(H1, W2b, bd2, nullptr, Wd3, out, 2048);
}

// Round 9
// 223.887 us; speedup vs baseline: 1.4763x; 1.4763x over previous
//
#include <hip/hip_runtime.h>
#include <hip/hip_bf16.h>

// LSTM_80960133529703: B=16384, T=24, F=7, H=8, L=4; dense 192->1024->2048->4.
// R8: back to R5's anchor structure (both operands LDS-staged, BK=64, XOR
//     swizzle, 4 blocks/CU). Change: MFMA shape 16x16x32 -> 32x32x16 (same
//     64x64 wave tile as 2x2 frags, same DS volume, MFMA pipe -17%, half the
//     MFMA instr issue). gemm1/gemm2 split into named kernels for profiling.
// ws: Y @0 | H1 @6291456 | W1b @39845888 | W2b @40239104
typedef __attribute__((ext_vector_type(4))) float f32x4;
typedef __attribute__((ext_vector_type(16))) float f32x16;
typedef __attribute__((ext_vector_type(2))) float f32x2;
typedef __attribute__((ext_vector_type(8))) short bf16x8;

__device__ __forceinline__ ushort f2bf(float f) {
    union { float f; uint u; } v; v.f = f;
    uint u = v.u;
    return (ushort)((u + 0x7fffu + ((u >> 16) & 1u)) >> 16);   // RNE
}
__device__ __forceinline__ float sigm(float x) {
    return __builtin_amdgcn_rcpf(1.0f + __builtin_amdgcn_exp2f(x * -1.442695040888963f));
}
__device__ __forceinline__ float tanh_(float x) {
    return 2.0f * __builtin_amdgcn_rcpf(1.0f + __builtin_amdgcn_exp2f(x * -2.885390081777927f)) - 1.0f;
}

typedef const __attribute__((address_space(1))) unsigned int ga_u32;
typedef __attribute__((address_space(3))) unsigned int lds_u32;
__device__ __forceinline__ void g2l16(const void* g, void* l) {
    __builtin_amdgcn_global_load_lds((ga_u32*)(unsigned long long)g,
                                     (lds_u32*)(unsigned int)(unsigned long long)l,
                                     16, 0, 0);
}

// ---------------------------------------------------------------- LSTM ----
struct LstmW {
    const float* wih[4];
    const float* whh[4];
    const float* bih[4];
    const float* bhh[4];
};

__device__ __forceinline__ void gates8p(const f32x2 w01[8], const f32x2 w23[8],
                                        const float xv8[8], f32x2& a01, f32x2& a23) {
#pragma unroll
    for (int k = 0; k < 8; ++k) {
        f32x2 xv = {xv8[k], xv8[k]};
        a01 += w01[k] * xv;
        a23 += w23[k] * xv;
    }
}
__device__ __forceinline__ void cellup(f32x2 a01, f32x2 a23, float& h, float& c) {
    c = sigm(a01.y) * c + sigm(a01.x) * tanh_(a23.x);
    h = sigm(a23.y) * tanh_(c);
}
__device__ __forceinline__ void ld8(const float* p, float v[8]) {
    float4 a = *(const float4*)p;
    float4 b = *(const float4*)(p + 4);
    v[0] = a.x; v[1] = a.y; v[2] = a.z; v[3] = a.w;
    v[4] = b.x; v[5] = b.y; v[6] = b.z; v[7] = b.w;
}

// blocks [0,512): LSTM; blocks [512, 512+560): weight cvt fp32->bf16 (+ out init)
__global__ __launch_bounds__(256) void pre_kernel(const float* __restrict__ x, LstmW p,
                                                  ushort* __restrict__ Y,
                                                  const float* __restrict__ W1,
                                                  const float* __restrict__ W2,
                                                  ushort* __restrict__ W1b,
                                                  ushort* __restrict__ W2b,
                                                  const float* __restrict__ b3,
                                                  float* __restrict__ out) {
    __shared__ float xs[32 * 168];
    __shared__ float hb[32 * 200];

    const int tid = threadIdx.x;
    if (blockIdx.x >= 512) {
        const int tg = (blockIdx.x - 512) * 256 + tid;
        if (tg < 16384) {
            float4 bv = {b3[0], b3[1], b3[2], b3[3]};
            ((float4*)out)[tg] = bv;
        }
#pragma unroll
        for (int s = 0; s < 4; ++s) {
            int i = tg + s * 143360;
            const float4* src; ushort4* dst; int off;
            if (i < 49152) { src = (const float4*)W1; dst = (ushort4*)W1b; off = i; }
            else { src = (const float4*)W2; dst = (ushort4*)W2b; off = i - 49152; }
            float4 v = src[off];
            ushort4 r; r.x = f2bf(v.x); r.y = f2bf(v.y); r.z = f2bf(v.z); r.w = f2bf(v.w);
            dst[off] = r;
        }
        return;
    }

    const int e0 = blockIdx.x * 32;
    {
        const float4* s = (const float4*)(x + (size_t)e0 * 168);
        float4* d = (float4*)xs;
        for (int i = tid; i < 1344; i += 256) d[i] = s[i];
    }
    __syncthreads();

    const int el = tid >> 3, j = tid & 7;
    float* hr = hb + el * 200;
    const float* xr = xs + el * 168;

    f32x2 wx01[8], wx23[8], wh01[8], wh23[8], b01, b23;

    // ---- layer 0 (in = 7) ----
    {
        const float* Wih = p.wih[0];
        const float* Whh = p.whh[0];
#pragma unroll
        for (int k = 0; k < 7; ++k) {
            wx01[k] = {Wih[(0 + j) * 7 + k], Wih[(8 + j) * 7 + k]};
            wx23[k] = {Wih[(16 + j) * 7 + k], Wih[(24 + j) * 7 + k]};
        }
#pragma unroll
        for (int k = 0; k < 8; ++k) {
            wh01[k] = {Whh[(0 + j) * 8 + k], Whh[(8 + j) * 8 + k]};
            wh23[k] = {Whh[(16 + j) * 8 + k], Whh[(24 + j) * 8 + k]};
        }
        b01 = {p.bih[0][j] + p.bhh[0][j], p.bih[0][8 + j] + p.bhh[0][8 + j]};
        b23 = {p.bih[0][16 + j] + p.bhh[0][16 + j], p.bih[0][24 + j] + p.bhh[0][24 + j]};

        float h = 0.f, c = 0.f;
        {
            f32x2 a01 = b01, a23 = b23;
#pragma unroll
            for (int k = 0; k < 7; ++k) {
                f32x2 xv = {xr[k], xr[k]};
                a01 += wx01[k] * xv; a23 += wx23[k] * xv;
            }
            cellup(a01, a23, h, c);
            hr[j] = h;
        }
        for (int t = 1; t < 24; ++t) {
            f32x2 a01 = b01, a23 = b23;
#pragma unroll
            for (int k = 0; k < 7; ++k) {
                f32x2 xv = {xr[t * 7 + k], xr[t * 7 + k]};
                a01 += wx01[k] * xv; a23 += wx23[k] * xv;
            }
            float hp[8]; ld8(&hr[(t - 1) * 8], hp);
            gates8p(wh01, wh23, hp, a01, a23);
            cellup(a01, a23, h, c);
            hr[t * 8 + j] = h;
        }
    }

    // ---- layers 1..3 ----
#pragma unroll
    for (int l = 1; l < 4; ++l) {
        const float* Wih = p.wih[l];
        const float* Whh = p.whh[l];
#pragma unroll
        for (int k = 0; k < 8; ++k) {
            wx01[k] = {Wih[(0 + j) * 8 + k], Wih[(8 + j) * 8 + k]};
            wx23[k] = {Wih[(16 + j) * 8 + k], Wih[(24 + j) * 8 + k]};
            wh01[k] = {Whh[(0 + j) * 8 + k], Whh[(8 + j) * 8 + k]};
            wh23[k] = {Whh[(16 + j) * 8 + k], Whh[(24 + j) * 8 + k]};
        }
        b01 = {p.bih[l][j] + p.bhh[l][j], p.bih[l][8 + j] + p.bhh[l][8 + j]};
        b23 = {p.bih[l][16 + j] + p.bhh[l][16 + j], p.bih[l][24 + j] + p.bhh[l][24 + j]};

        float h = 0.f, c = 0.f;
        {
            float xin[8]; ld8(&hr[0], xin);
            f32x2 a01 = b01, a23 = b23;
            gates8p(wx01, wx23, xin, a01, a23);
            cellup(a01, a23, h, c);
            hr[j] = h;
            if (l == 3) Y[((size_t)(e0 + el) * 24) * 8 + j] = f2bf(h);
        }
        for (int t = 1; t < 24; ++t) {
            float xin[8]; ld8(&hr[t * 8], xin);
            float hp[8];  ld8(&hr[(t - 1) * 8], hp);
            f32x2 a01 = b01, a23 = b23;
            gates8p(wx01, wx23, xin, a01, a23);
            gates8p(wh01, wh23, hp, a01, a23);
            cellup(a01, a23, h, c);
            hr[t * 8 + j] = h;
            if (l == 3) Y[((size_t)(e0 + el) * 24 + t) * 8 + j] = f2bf(h);
        }
    }
}

// ---------------------------------------------------------------- GEMM ----
// Tile 128x128, BK=64, 4 waves; wave tile 64x64 as 2x2 of mfma_32x32x16.
// LDS [128][64] bf16 per tensor, XOR-chunk-swizzled (chunk^=(row&7)), staged
// via global_load_lds (16B). Frag reads: row = base + (lane&31),
// k = ks*16 + (lane>>5)*8 -> chunk (ks*2 + (lane>>5)) ^ (row&7).
// C/D layout (m74/m101): col = lane&31, row = (reg&3) + 8*(reg>>2) + 4*(lane>>5).
// FUSE3: two-pass f32 Cs[64][132] + w3s[4][132], b128 dots, atomics into out.
template <int KDIM, bool FUSE3>
__device__ __forceinline__ void gemm_body(const ushort* __restrict__ A,
                                          const ushort* __restrict__ W,
                                          const float* __restrict__ bias,
                                          ushort* __restrict__ Hout,
                                          const float* __restrict__ W3,
                                          float* __restrict__ outf, int N) {
    constexpr int SMEMN = FUSE3 ? 16896 : 16384;   // ushorts; FUSE3: Cs 64x132 f32
    __shared__ alignas(16) ushort smem[SMEMN];
    __shared__ alignas(16) float w3s[FUSE3 ? 528 : 1];
    ushort* As = smem;            // [128][64] swizzled
    ushort* Ws = smem + 8192;

    const int tid = threadIdx.x;
    const int m0 = blockIdx.x * 128;
    const int n0 = blockIdx.y * 128;
    const int lane = tid & 63;
    const int wv = tid >> 6;
    const int wm = (wv & 1) * 64;
    const int wn = (wv >> 1) * 64;
    const int l31 = lane & 31;
    const int kh = lane >> 5;

    if (FUSE3) {
        for (int i = tid; i < 512; i += 256)
            w3s[(i >> 7) * 132 + (i & 127)] = W3[(size_t)(i >> 7) * 2048 + n0 + (i & 127)];
    }

    // staging: per wave, 4 calls/tensor; call c: rows wv*32 + c*8 + lrow
    const int lrow = lane >> 3;
    const int lchunk = (lane & 7) ^ lrow;          // XOR swizzle at source
    const ushort* Ag = A + (size_t)(m0 + wv * 32 + lrow) * KDIM + lchunk * 8;
    const ushort* Wg = W + (size_t)(n0 + wv * 32 + lrow) * KDIM + lchunk * 8;
    ushort* Ald = As + wv * 2048;
    ushort* Wld = Ws + wv * 2048;

    // frag-read base addresses (row&7 == l31&7); chunk varies per ks
    const int r7 = l31 & 7;
    const int arow0 = (wm + l31) * 64;        // mi=0; mi=1 adds 32*64
    const int brow0 = (wn + l31) * 64;

    f32x16 acc[2][2];
#pragma unroll
    for (int mi = 0; mi < 2; ++mi)
#pragma unroll
        for (int ni = 0; ni < 2; ++ni)
#pragma unroll
            for (int r = 0; r < 16; ++r) acc[mi][ni][r] = 0.f;

    for (int k0 = 0; k0 < KDIM; k0 += 64) {
#pragma unroll
        for (int c = 0; c < 4; ++c)
            g2l16(Ag + (size_t)c * 8 * KDIM + k0, Ald + c * 512);
#pragma unroll
        for (int c = 0; c < 4; ++c)
            g2l16(Wg + (size_t)c * 8 * KDIM + k0, Wld + c * 512);
        __syncthreads();

#pragma unroll
        for (int ks = 0; ks < 4; ++ks) {
            const int ck = ((ks * 2 + kh) ^ r7) * 8;
            bf16x8 afr[2], bfr[2];
#pragma unroll
            for (int mi = 0; mi < 2; ++mi)
                afr[mi] = *(const bf16x8*)&As[arow0 + mi * 2048 + ck];
#pragma unroll
            for (int ni = 0; ni < 2; ++ni)
                bfr[ni] = *(const bf16x8*)&Ws[brow0 + ni * 2048 + ck];
#pragma unroll
            for (int mi = 0; mi < 2; ++mi)
#pragma unroll
                for (int ni = 0; ni < 2; ++ni)
                    acc[mi][ni] = __builtin_amdgcn_mfma_f32_32x32x16_bf16(afr[mi], bfr[ni],
                                                                         acc[mi][ni], 0, 0, 0);
        }
        __syncthreads();
    }

    if (!FUSE3) {
#pragma unroll
        for (int ni = 0; ni < 2; ++ni) {
            const int col = n0 + wn + ni * 32 + l31;
            const float b = bias[col];
#pragma unroll
            for (int mi = 0; mi < 2; ++mi)
#pragma unroll
                for (int r = 0; r < 16; ++r) {
                    const int row = m0 + wm + mi * 32 + (r & 3) + 8 * (r >> 2) + 4 * kh;
                    Hout[(size_t)row * N + col] = f2bf(fmaxf(acc[mi][ni][r] + b, 0.f));
                }
        }
    } else {
        // Two passes over 64-row halves; Cs [64][132] f32 overlays smem.
        float* Cs = (float*)smem;
        const int drow = tid >> 2;
        const int dn = tid & 3;
#pragma unroll
        for (int pass = 0; pass < 2; ++pass) {
            if ((wv & 1) == pass) {
#pragma unroll
                for (int ni = 0; ni < 2; ++ni) {
                    const int cl = wn + ni * 32 + l31;
                    const float b = bias[n0 + cl];
#pragma unroll
                    for (int mi = 0; mi < 2; ++mi)
#pragma unroll
                        for (int r = 0; r < 16; ++r) {
                            const int rl = mi * 32 + (r & 3) + 8 * (r >> 2) + 4 * kh;  // 0..63
                            Cs[rl * 132 + cl] = fmaxf(acc[mi][ni][r] + b, 0.f);
                        }
                }
            }
            __syncthreads();
            const float* crow = &Cs[drow * 132];
            const float* wrow = &w3s[dn * 132];
            float p = 0.f;
#pragma unroll
            for (int ch = 0; ch < 32; ++ch) {
                f32x4 cv = *(const f32x4*)(crow + ch * 4);
                f32x4 wv4 = *(const f32x4*)(wrow + ch * 4);
                p += cv[0] * wv4[0] + cv[1] * wv4[1] + cv[2] * wv4[2] + cv[3] * wv4[3];
            }
            atomicAdd(&outf[(size_t)(m0 + pass * 64 + drow) * 4 + dn], p);
            __syncthreads();
        }
    }
}

__global__ __launch_bounds__(256, 4) void gemm1_kernel(const ushort* __restrict__ A,
                                                       const ushort* __restrict__ W,
                                                       const float* __restrict__ bias,
                                                       ushort* __restrict__ Hout, int N) {
    gemm_body<192, false>(A, W, bias, Hout, nullptr, nullptr, N);
}
__global__ __launch_bounds__(256, 4) void gemm2_kernel(const ushort* __restrict__ A,
                                                       const ushort* __restrict__ W,
                                                       const float* __restrict__ bias,
                                                       const float* __restrict__ W3,
                                                       float* __restrict__ outf) {
    gemm_body<1024, true>(A, W, bias, nullptr, W3, outf, 2048);
}

// -------------------------------------------------------------- launch ----
extern "C" void kernel_launch(void* const* d_in, const int* in_sizes, int n_in,
                              void* d_out, int out_size, void* d_ws, size_t ws_size,
                              hipStream_t stream) {
    const float* x = (const float*)d_in[0];
    LstmW w;
    for (int l = 0; l < 4; ++l) {
        w.wih[l] = (const float*)d_in[1 + 4 * l];
        w.whh[l] = (const float*)d_in[2 + 4 * l];
        w.bih[l] = (const float*)d_in[3 + 4 * l];
        w.bhh[l] = (const float*)d_in[4 + 4 * l];
    }
    const float* Wd1 = (const float*)d_in[17];
    const float* bd1 = (const float*)d_in[18];
    const float* Wd2 = (const float*)d_in[19];
    const float* bd2 = (const float*)d_in[20];
    const float* Wd3 = (const float*)d_in[21];
    const float* bd3 = (const float*)d_in[22];
    float* out = (float*)d_out;

    ushort* Y   = (ushort*)d_ws;
    ushort* H1  = (ushort*)((char*)d_ws + 6291456);
    ushort* W1b = (ushort*)((char*)d_ws + 39845888);
    ushort* W2b = (ushort*)((char*)d_ws + 40239104);

    pre_kernel<<<1072, 256, 0, stream>>>(x, w, Y, Wd1, Wd2, W1b, W2b, bd3, out);
    gemm1_kernel<<<dim3(128, 8), 256, 0, stream>>>(Y, W1b, bd1, H1, 1024);
    gemm2_kernel<<<dim3(128, 16), 256, 0, stream>>>(H1, W2b, bd2, Wd3, out);
}